// Round 4
// baseline (573.572 us; speedup 1.0000x reference)
//
#include <hip/hip_runtime.h>

#define BATCHN 4096
#define NSTEPS 5000
#define NSTIM  4000
#define U      25                  // steps per eps register block
#define NBLK      (NSTEPS / U)     // 200
#define NBLK_STIM (NSTIM / U)      // 160
#define ELPB   32                  // batch elements per workgroup (1 wave)

// 128 blocks x 64 threads (ONE wave, no LDS, no barriers). Lane pair per
// element: lane 2e = unit1, lane 2e+1 = unit2; coupling via DPP quad_perm.
// R2==R3 (280 vs 287 us) proved the kernel is dependency-chain-bound:
// 138 cy/step = dpp+fma(14) + exp2(~54) + fma(4) + rcp(~54) + tail(12).
// The two hardware transcendentals are ~78% of the chain. This round
// replaces BOTH with short FMA chains:
//   exp2: rndne range-reduce + degree-7 Estrin poly (4-deep) + exact
//         exponent bit-add. Chain ~24 cy, rel err <= ~1e-7 (same class as
//         the hw-rcp-vs-exact-divide deviation already validated).
//   rcp:  bit-magic seed (~5% err) + 3 Newton iters on |den| (-> ~1e-8),
//         sign folded into w via xor off-chain. Chain ~36 cy.
// Everything else is verbatim R3: register-double-buffered eps stream,
// on-lane In recurrence, on-lane crossing bookkeeping, wave-uniform exit.
static __device__ __forceinline__ float swap_pair(float v) {
    // quad_perm(1,0,3,2) = 0xB1 : swap adjacent lanes within each pair
    return __int_as_float(
        __builtin_amdgcn_mov_dpp(__float_as_int(v), 0xB1, 0xF, 0xF, true));
}

__global__ __launch_bounds__(64, 1) void ww_kernel(
    const float* __restrict__ input_signal,
    const float* __restrict__ sJ11, const float* __restrict__ sJ12,
    const float* __restrict__ sJ21, const float* __restrict__ sJ22,
    const float* __restrict__ sJext, const float* __restrict__ sI0,
    const float* __restrict__ sNoise, const float* __restrict__ sThr,
    const float* __restrict__ sDelay,
    const float* __restrict__ eps0_1, const float* __restrict__ eps0_2,
    const float* __restrict__ eps_1, const float* __restrict__ eps_2,
    float* __restrict__ out)
{
    const int lane = threadIdx.x;        // 0..63
    const int unit = lane & 1;
    const int b    = blockIdx.x * ELPB + (lane >> 1);

    const float KE = -0.22217503629690245f;   // -0.154/ln2

    const float J11 = sJ11[0], J12 = sJ12[0], J21 = sJ21[0], J22 = sJ22[0];
    const float K270 = KE * 270.0f;
    const float B11 = K270 * J11, nB12 = -K270 * J12;
    const float B22 = K270 * J22, nB21 = -K270 * J21;
    const float Bs = unit ? B22 : B11;        // self coefficient
    const float Bc = unit ? nB21 : nB12;      // cross coefficient
    const float nKE  = -KE;                   // +0.2221750363
    const float KE1p = 1.000001f * KE;        // KE*(1+1e-6)
    const float SM = 0.995f;                  // 1 - DT/tau_s
    const float QC = 3.205e-4f;               // gamma/1000*DT

    const float noise = sNoise[0];
    const float Jext = sJext[0], I0 = sI0[0];
    const float thr = sThr[0], delay = sDelay[0];

    // u-space stimulus offsets P = 270*(I0+I)-108, pre-scaled by KE
    const float inp = input_signal[b];
    const float Pself = unit
        ? fmaf(270.0f, I0 + Jext * (1.0f - inp * 0.01f), -108.0f)
        : fmaf(270.0f, I0 + Jext * (1.0f + inp * 0.01f), -108.0f);
    const float Pn  = fmaf(270.0f, I0, -108.0f);
    const float KPs = KE * Pself, KPn = KE * Pn;

    const float decay = 0.7788007830714049f;          // exp(-0.25)
    const float kKE   = KE * noise * 0.4435478165294536f * 270.0f;
    const float n270K = noise * 270.0f * KE;

    const float* __restrict__ ep = (unit ? eps_2 : eps_1) + b;
    float VK = (unit ? eps0_2[b] : eps0_1[b]) * n270K;   // KE*270*In

    float s = 0.1f;
    const float INF = __builtin_inff();
    float tm = INF;                  // first-crossing step of MY unit
    float tf = 0.0f;

    float bufA[U], bufB[U];          // double-buffered eps registers

    auto loadE = [&](float (&buf)[U], int blk) {
        const size_t off = (size_t)blk * ((size_t)U * BATCHN);
        #pragma unroll
        for (int i = 0; i < U; ++i)
            buf[i] = ep[off + (size_t)i * BATCHN];
    };

    // 2^f Taylor coefficients (degree 7; |R8| ~ 5e-9 rel on [-0.5,0.5])
    const float C1 = 0.6931471805599453f;
    const float C2 = 0.2402265069591007f;
    const float C3 = 0.0555041086648216f;
    const float C4 = 0.0096181291076285f;
    const float C5 = 0.0013333558146428f;
    const float C6 = 0.0001540353009338f;
    const float C7 = 1.5240437e-5f;

    // One U-step block; returns true when every element in the wave decided.
    auto stepBlk = [&](const float (&buf)[U], int blk) -> bool {
        const float KP = (blk < NBLK_STIM) ? KPs : KPn;
        #pragma unroll
        for (int i = 0; i < U; ++i) {
            float kc = VK + KP;                  // step t uses In_t (off-chain)
            VK = fmaf(VK, decay, kKE * buf[i]);  // then In += eps_t (off-chain)
            float sc = swap_pair(s);             // partner unit, step t-1
            float w  = fmaf(Bs, s, fmaf(Bc, sc, kc));

            // ---- x = 2^w, FMA-chain form (chain ~24 cy vs hw ~54) ----
            float nf = __builtin_rintf(w);
            int   ni = (int)nf;
            float f  = w - nf;                   // f in [-0.5, 0.5]
            float f2 = f * f;
            float f4 = f2 * f2;
            float t1 = fmaf(f, C1, 1.0f);
            float t2 = fmaf(f, C3, C2);
            float t3 = fmaf(f, C5, C4);
            float t4 = fmaf(f, C7, C6);
            float u1 = fmaf(f2, t2, t1);
            float u2 = fmaf(f2, t4, t3);
            float p  = fmaf(f4, u2, u1);         // 2^f, p in [0.707, 1.415]
            float x  = __int_as_float(__float_as_int(p) + (ni << 23));

            // ---- r = 1/den, magic seed + 3 Newton (chain ~36 cy) ----
            float den = fmaf(nKE, x, KE1p);      // KE*(1.000001 - x)
            int   di  = __float_as_int(den);
            int   sb  = di & 0x80000000;         // sign(den), folded into w
            float ad  = __int_as_float(di & 0x7fffffff);
            float r0  = __int_as_float(0x7EF311C3 - (di & 0x7fffffff));
            float tN;
            tN = fmaf(-ad, r0, 2.0f); float r1 = r0 * tN;
            tN = fmaf(-ad, r1, 2.0f); float r2 = r1 * tN;
            tN = fmaf(-ad, r2, 2.0f); float r3 = r2 * tN;
            float ws = __int_as_float(__float_as_int(w) ^ sb);

            // h = relu(w/den); same extreme behavior as validated hw path:
            // den large -> r3 ~ 0 -> h -> 0; den -> 0 -> huge |h|, relu clips
            // the negative side exactly like ref's relu.
            float h  = fmaxf(ws * r3, 0.0f);
            s = fmaf(h, fmaf(-QC, s, QC), SM * s);
            tm = fminf(tm, (s > thr) ? tf : INF);   // post-update, like ref
            tf += 1.0f;
        }
        float pm = fminf(tm, swap_pair(tm));     // element decided iff either unit
        return __all(pm < INF);
    };

    loadE(bufA, 0);
    for (int blk = 0; blk < NBLK; blk += 2) {
        loadE(bufB, blk + 1);                    // issue next block's eps early
        if (stepBlk(bufA, blk)) break;
        if (blk + 2 < NBLK) loadE(bufA, blk + 2);
        if (stepBlk(bufB, blk + 1)) break;
    }

    // Pair-combine: even lane holds t1, partner holds t2.
    float to = swap_pair(tm);
    if (unit == 0) {
        float t1 = tm, t2 = to;
        // Epilogue (validated prior session R2-R4). Never-deciders: ref=-inf;
        // emit finite sentinel so harness absmax is inf, not nan.
        float o;
        if (t1 == INF && t2 == INF) {
            o = -3.0e38f;
        } else {
            float dtm = (t1 < t2) ? t1 : -t2;
            o = dtm * 0.5f;                  // * DT -> ms
            if (o < 0.0f)      o = o / 1000.0f - delay;
            else if (o > 0.0f) o = o / 1000.0f + delay;
        }
        out[b] = o;
    }
}

extern "C" void kernel_launch(void* const* d_in, const int* in_sizes, int n_in,
                              void* d_out, int out_size, void* d_ws, size_t ws_size,
                              hipStream_t stream) {
    ww_kernel<<<dim3(BATCHN / ELPB), dim3(64), 0, stream>>>(
        (const float*)d_in[0],   // input_signal [4096]
        (const float*)d_in[1],   // J11
        (const float*)d_in[2],   // J12
        (const float*)d_in[3],   // J21
        (const float*)d_in[4],   // J22
        (const float*)d_in[5],   // J_ext
        (const float*)d_in[6],   // I_0
        (const float*)d_in[7],   // noise_ampa
        (const float*)d_in[8],   // threshold
        (const float*)d_in[9],   // motor_delay
        (const float*)d_in[10],  // eps0_1 [4096]
        (const float*)d_in[11],  // eps0_2 [4096]
        (const float*)d_in[12],  // eps_1 [5000*4096]
        (const float*)d_in[13],  // eps_2 [5000*4096]
        (float*)d_out);          // [4096]
}